// Round 4
// baseline (220.933 us; speedup 1.0000x reference)
//
#include <hip/hip_runtime.h>
#include <stdint.h>
#include <stddef.h>

// ---------------------------------------------------------------------------
// B=4, N=2048, D=768, H=12, HD=64. BN=8192.
// I/O fp32; internal bf16 MFMA + fp32 accum.
// qkv hidden [8192][2304] bf16 (Q 0..767 | K 768..1535 | V 1536..2303).
// V also materialized transposed: VT[(b*12+h)*64+d][2048 j] (aliases xb).
// Attention overwrites the Q region in place with merged-head output.
// attn v10: fragment-order LDS (zero-conflict reads, v9-verified) + COALESCED
// staging: global->reg (8 rows x 128B per b128 load, v8 pattern) then
// ds_write_b128 to frag-order slot with lane-perm p(g,hi)=(((g&3)<<1)|hi)
// ^((g>>2)<<1) -> each consecutive-8-lane octet hits 8 distinct bank groups
// (zero write conflicts); reads are within-stripe XOR of linear (zero read
// conflicts). T14 split: loads issue post-barrier, writes land pre-barrier ->
// global latency hides under tile compute. setprio removed (lockstep barrier
// structure, m190). In-register softmax (swapped 32x32x16 QK^T, cvt_pk_bf16 +
// permlane32_swap) unchanged from v7/v8/v9 (verified).
// ---------------------------------------------------------------------------

typedef __bf16 bf16x8 __attribute__((ext_vector_type(8)));
typedef float  f32x4  __attribute__((ext_vector_type(4)));
typedef float  f32x16 __attribute__((ext_vector_type(16)));
typedef unsigned int u32x2 __attribute__((ext_vector_type(2)));

__device__ __forceinline__ float bf2f(unsigned short u){
  union { unsigned int i; float f; } x; x.i = ((unsigned int)u) << 16; return x.f;
}
// round-half-up bf16
__device__ __forceinline__ unsigned short fast2bf(float f){
  union { float f; unsigned int i; } x; x.f = f;
  return (unsigned short)((x.i + 0x8000u) >> 16);
}
// single-instruction packed fp32->bf16 pair (RNE)
__device__ __forceinline__ unsigned int cvtpk_bf16(float lo, float hi){
  unsigned int r;
  asm("v_cvt_pk_bf16_f32 %0, %1, %2" : "=v"(r) : "v"(lo), "v"(hi));
  return r;
}
// v_permlane32_swap_b32: a' = {a.lo32lanes, b.lo32lanes}, b' = {a.hi, b.hi}
__device__ __forceinline__ void plswap32(unsigned int &a, unsigned int &b){
#if __has_builtin(__builtin_amdgcn_permlane32_swap)
  u32x2 r = __builtin_amdgcn_permlane32_swap(a, b, false, false);
  a = r.x; b = r.y;
#else
  asm volatile("v_permlane32_swap_b32 %0, %1" : "+v"(a), "+v"(b));
#endif
}

#if __has_builtin(__builtin_amdgcn_exp2f)
  #define EXP2F(x) __builtin_amdgcn_exp2f(x)
#else
  #define EXP2F(x) exp2f(x)
#endif

// async global->LDS, 16B per lane; LDS dest = wave-uniform base + lane*16.
#define GLD16(gp, lp) __builtin_amdgcn_global_load_lds( \
  (__attribute__((address_space(1))) void*)(uintptr_t)(gp), \
  (__attribute__((address_space(3))) void*)(unsigned int)(uintptr_t)(lp), 16, 0, 0)

// ---------------------------------------------------------------------------
__global__ void f32_to_bf16(const float* __restrict__ in,
                            unsigned short* __restrict__ out, int n){
  int i = (blockIdx.x * 256 + threadIdx.x) * 4;
  if(i < n){
    float4 v = *(const float4*)(in + i);
    ushort4 o;
    o.x = fast2bf(v.x); o.y = fast2bf(v.y); o.z = fast2bf(v.z); o.w = fast2bf(v.w);
    *(ushort4*)(out + i) = o;
  }
}

// ---------------------------------------------------------------------------
__global__ void transpose_f32_bf16(const float* __restrict__ W,
                                   unsigned short* __restrict__ Wt, int K, int N){
  __shared__ float tile[32][33];
  int n0 = blockIdx.x * 32, k0 = blockIdx.y * 32;
  int tx = threadIdx.x, ty = threadIdx.y;   // (32,8)
  for(int i = ty; i < 32; i += 8) tile[i][tx] = W[(size_t)(k0 + i) * N + (n0 + tx)];
  __syncthreads();
  for(int i = ty; i < 32; i += 8) Wt[(size_t)(n0 + i) * K + (k0 + tx)] = fast2bf(tile[tx][i]);
}

// ---------------------------------------------------------------------------
// V transpose: VT[(b*12+h)*64 + d][j] = qkv[b*2048+j][1536 + h*64 + d]
// ---------------------------------------------------------------------------
__global__ __launch_bounds__(256) void transpose_v(const unsigned short* __restrict__ qkv,
                                                   unsigned short* __restrict__ VT){
  __shared__ __align__(16) unsigned short Ts[64*72];
  const int t  = threadIdx.x;
  const int jt = blockIdx.x;        // 0..31
  const int bh = blockIdx.y;        // 0..47
  const int b = bh / 12, h = bh - b*12;
  const unsigned short* src = qkv + (size_t)(b*2048 + jt*64)*2304 + 1536 + h*64;
  #pragma unroll
  for(int c = t; c < 512; c += 256){
    int j = c >> 3, d0 = (c & 7) * 8;
    *(uint4*)&Ts[j*72 + d0] = *(const uint4*)(src + (size_t)j*2304 + d0);
  }
  __syncthreads();
  unsigned short* dst = VT + (size_t)bh*64*2048 + jt*64;
  #pragma unroll
  for(int c = t; c < 512; c += 256){
    int d = c >> 3, j0 = (c & 7) * 8;
    ushort4 lo, hi;
    lo.x = Ts[(j0+0)*72 + d]; lo.y = Ts[(j0+1)*72 + d];
    lo.z = Ts[(j0+2)*72 + d]; lo.w = Ts[(j0+3)*72 + d];
    hi.x = Ts[(j0+4)*72 + d]; hi.y = Ts[(j0+5)*72 + d];
    hi.z = Ts[(j0+6)*72 + d]; hi.w = Ts[(j0+7)*72 + d];
    *(ushort4*)(dst + (size_t)d*2048 + j0)     = lo;
    *(ushort4*)(dst + (size_t)d*2048 + j0 + 4) = hi;
  }
}

// ---------------------------------------------------------------------------
// MFMA GEMM-BT v2: C = A*Bt^T + bias. 128x128 tile, BK=32, DOUBLE-BUFFERED
// global_load_lds.
// ---------------------------------------------------------------------------
template<typename OT>
__global__ __launch_bounds__(256) void gemm_bt(const unsigned short* __restrict__ A,
                                               const unsigned short* __restrict__ Bt,
                                               const float* __restrict__ bias,
                                               OT* __restrict__ C,
                                               int M, int N, int K, int lda){
  __shared__ __align__(16) unsigned short As[2][128*32];
  __shared__ __align__(16) unsigned short Bs[2][128*32];
  const int tid  = threadIdx.x;
  const int lane = tid & 63, w = tid >> 6;
  const int m0 = blockIdx.y * 128, n0 = blockIdx.x * 128;

  f32x4 acc[4][4];
  #pragma unroll
  for(int i=0;i<4;i++)
    #pragma unroll
    for(int j=0;j<4;j++) acc[i][j] = (f32x4){0.f,0.f,0.f,0.f};

  const int c0 = w*64 + lane, c1 = c0 + 256;
  const unsigned short* Ag0 = A  + (size_t)(m0 + (c0>>2)) * lda + (c0&3)*8;
  const unsigned short* Ag1 = A  + (size_t)(m0 + (c1>>2)) * lda + (c1&3)*8;
  const unsigned short* Bg0 = Bt + (size_t)(n0 + (c0>>2)) * K   + (c0&3)*8;
  const unsigned short* Bg1 = Bt + (size_t)(n0 + (c1>>2)) * K   + (c1&3)*8;

  const int wm = w & 1, wn = w >> 1;
  const int quad = lane >> 4, l15 = lane & 15;

  // prologue: stage tile 0 into buffer 0
  GLD16(Ag0, As[0] +        w*512);
  GLD16(Ag1, As[0] + 2048 + w*512);
  GLD16(Bg0, Bs[0] +        w*512);
  GLD16(Bg1, Bs[0] + 2048 + w*512);

  int cur = 0;
  for(int kt = 0; kt < K; kt += 32){
    __syncthreads();               // drains GLD16(cur) for all waves
    if(kt + 32 < K){               // issue next tile into the other buffer
      int nx = cur ^ 1;
      GLD16(Ag0 + kt + 32, As[nx] +        w*512);
      GLD16(Ag1 + kt + 32, As[nx] + 2048 + w*512);
      GLD16(Bg0 + kt + 32, Bs[nx] +        w*512);
      GLD16(Bg1 + kt + 32, Bs[nx] + 2048 + w*512);
    }

    bf16x8 af[4], bfr[4];
    #pragma unroll
    for(int mt=0;mt<4;mt++) af[mt]  = *(const bf16x8*)&As[cur][(wm*64 + mt*16 + l15)*32 + quad*8];
    #pragma unroll
    for(int nt=0;nt<4;nt++) bfr[nt] = *(const bf16x8*)&Bs[cur][(wn*64 + nt*16 + l15)*32 + quad*8];
    #pragma unroll
    for(int mt=0;mt<4;mt++)
      #pragma unroll
      for(int nt=0;nt<4;nt++)
        acc[mt][nt] = __builtin_amdgcn_mfma_f32_16x16x32_bf16(af[mt], bfr[nt], acc[mt][nt], 0, 0, 0);
    cur ^= 1;
  }

  // epilogue: C/D layout col=lane&15, row=quad*4+reg
  #pragma unroll
  for(int nt=0;nt<4;nt++){
    int col = n0 + wn*64 + nt*16 + l15;
    float bv = bias[col];
    #pragma unroll
    for(int mt=0;mt<4;mt++){
      int row0 = m0 + wm*64 + mt*16 + quad*4;
      #pragma unroll
      for(int i=0;i<4;i++){
        float v = acc[mt][nt][i] + bv;
        if constexpr (sizeof(OT) == 2)
          C[(size_t)(row0 + i) * N + col] = (OT)fast2bf(v);
        else
          C[(size_t)(row0 + i) * N + col] = (OT)v;
      }
    }
  }
}

// ---------------------------------------------------------------------------
// MFMA flash attention v10 — frag-order LDS, coalesced reg-staging.
//
// Block = 256 threads = 4 waves; wave w owns q-rows q0 = bx*128 + w*32.
// 1-D grid 768 blocks, XCD-clustered remap (16 blocks sharing (b,h) -> 1 XCD).
//
// LDS (per 64-k tile, double-buffered): KV[buf] = K 8 groups x 1KB | V 8 x 1KB.
//   Frag slot (g, sl): the 16B lane sl reads for fragment-group g.
//   Physical slot-lane = sl ^ p,  p(g,hi) = (((g&3)<<1)|hi) ^ ((g>>2)<<1), hi=sl>>5.
//   Reads:  addr = g*1024 + (lane*16 ^ hi*16 ^ e(g)*32), e(g)=(g&3)^(g>>2):
//           within-128B-stripe permutation of linear -> 0 conflicts.
//   Writes: lane holds row w*8+(lane>>3) (+32L), chunk c8=lane&7 from a
//           coalesced b128 global load (8 rows x 128B/instr); each octet's 8
//           dests hit 8 distinct bank groups -> 0 conflicts.
// T14: global loads for tile n+1 issue at top of tile n's compute; ds_writes
// land after compute, before the single per-tile barrier.
// Per 32-k step: S^T = mfma(K,Q) x4 (q lane-local), p=exp2 (4 indep l-accums),
// P-frags via 8x cvt_pk_bf16 + 4x permlane32_swap, O += mfma(P,V) x4.
// ---------------------------------------------------------------------------
__global__ __launch_bounds__(256, 3) void attn_mfma(unsigned short* __restrict__ qkv,
                                                    const unsigned short* __restrict__ VT){
  __shared__ __align__(16) unsigned short KV[2][8192];   // 16KB per buffer: K|V
  __shared__ float linv_lds[4*32];

  const int t    = threadIdx.x;
  const int lane = t & 63, w = t >> 6;
  const int l31  = lane & 31, hi = lane >> 5;

  // XCD-clustered bijective remap: 768 % 8 == 0.
  const int bid = blockIdx.x;
  const int wg  = (bid & 7) * 96 + (bid >> 3);
  const int b   = wg / 192;                   // 16*12 = 192
  const int rem = wg - b * 192;
  const int h   = rem >> 4;
  const int bx  = rem & 15;
  const int q0  = bx * 128 + w * 32;

  unsigned short* Qg = qkv + (size_t)(b*2048 + q0)*2304 + h*64;

  // ---- Q B-frags: qf[c] = Q[q=l31][d = c*16 + hi*8 + 0..7], pre-scaled ----
  const float QSCALE = 0.125f * 1.4426950408889634f;
  bf16x8 qf[4];
  #pragma unroll
  for(int c=0;c<4;c++){
    uint4 raw = *(const uint4*)(Qg + (size_t)l31*2304 + c*16 + hi*8);
    const unsigned short* rp = (const unsigned short*)&raw;
    unsigned short o[8];
    #pragma unroll
    for(int e=0;e<8;e++) o[e] = fast2bf(bf2f(rp[e]) * QSCALE);
    qf[c] = *(const bf16x8*)o;
  }

  f32x16 oacc0, oacc1;
  #pragma unroll
  for(int i=0;i<16;i++){ oacc0[i] = 0.f; oacc1[i] = 0.f; }
  float lp0=0.f, lp1=0.f, lp2=0.f, lp3=0.f;

  // ---- staging geometry: lane loads row w*8+r8 (+32L), 16B chunk c8 ----
  const int r8 = lane >> 3, c8 = lane & 7;
  const unsigned short* gK = qkv + (size_t)(b*2048)*2304 + 768 + h*64
                           + (size_t)(w*8 + r8)*2304 + c8*8;
  const unsigned short* gV = VT + (size_t)(b*12 + h)*64*2048
                           + (size_t)(w*8 + r8)*2048 + c8*8;

  // ds_write byte offsets (lane-constant). K: g=L*4+(c8>>1), p=c8^(L<<1).
  // V: g=(c8>>2)*4+((c8>>1)&1)*2+L, p=(((g&3)<<1)|(c8&1))^((g>>2)<<1).
  int kwoff[2], vwoff[2];
  #pragma unroll
  for(int L=0; L<2; ++L){
    int sl = w*8 + r8 + 32*(c8&1);
    kwoff[L] = (L*4 + (c8>>1))*1024 + ((sl ^ (c8 ^ (L<<1))) * 16);
    int gVg  = (c8>>2)*4 + ((c8>>1)&1)*2 + L;
    int pV   = ((((gVg&3)<<1) | (c8&1)) ^ ((gVg>>2)<<1));
    vwoff[L] = 8192 + gVg*1024 + ((sl ^ pV) * 16);
  }

  // read base: lane*16 ^ hi*16; per-group XOR e(g)*32, e(g)=(g&3)^(g>>2)
  const int lin2 = (lane*16) ^ (hi*16);
  const int EG[8] = {0, 32, 64, 96, 32, 0, 96, 64};

  // ---- prologue: load + write tile 0 into buffer 0 ----
  uint4 ka0 = *(const uint4*)(gK);
  uint4 ka1 = *(const uint4*)(gK + (size_t)32*2304);
  uint4 va0 = *(const uint4*)(gV);
  uint4 va1 = *(const uint4*)(gV + (size_t)32*2048);
  {
    char* W0 = (char*)KV[0];
    *(uint4*)(W0 + kwoff[0]) = ka0;
    *(uint4*)(W0 + kwoff[1]) = ka1;
    *(uint4*)(W0 + vwoff[0]) = va0;
    *(uint4*)(W0 + vwoff[1]) = va1;
  }

  int cur = 0;
  #pragma unroll 1
  for(int it = 0; it < 32; ++it){
    __syncthreads();               // KV[cur] fully written, safe to read
    if(it + 1 < 32){               // issue next tile's coalesced loads now
      gK += (size_t)64*2304;
      gV += 64;
      ka0 = *(const uint4*)(gK);
      ka1 = *(const uint4*)(gK + (size_t)32*2304);
      va0 = *(const uint4*)(gV);
      va1 = *(const uint4*)(gV + (size_t)32*2048);
    }
    const char* Kc = (const char*)KV[cur];

    #pragma unroll
    for(int ks = 0; ks < 2; ++ks){
      // ---- K frags (0-conflict permuted-linear reads) ----
      bf16x8 kf0 = *(const bf16x8*)(Kc + (ks*4 + 0)*1024 + (lin2 ^ EG[ks*4 + 0]));
      bf16x8 kf1 = *(const bf16x8*)(Kc + (ks*4 + 1)*1024 + (lin2 ^ EG[ks*4 + 1]));
      bf16x8 kf2 = *(const bf16x8*)(Kc + (ks*4 + 2)*1024 + (lin2 ^ EG[ks*4 + 2]));
      bf16x8 kf3 = *(const bf16x8*)(Kc + (ks*4 + 3)*1024 + (lin2 ^ EG[ks*4 + 3]));

      // ---- S^T tile: 32k x 32q ----
      f32x16 sacc;
      #pragma unroll
      for(int i=0;i<16;i++) sacc[i] = 0.f;
      sacc = __builtin_amdgcn_mfma_f32_32x32x16_bf16(kf0, qf[0], sacc, 0, 0, 0);
      sacc = __builtin_amdgcn_mfma_f32_32x32x16_bf16(kf1, qf[1], sacc, 0, 0, 0);
      sacc = __builtin_amdgcn_mfma_f32_32x32x16_bf16(kf2, qf[2], sacc, 0, 0, 0);
      sacc = __builtin_amdgcn_mfma_f32_32x32x16_bf16(kf3, qf[3], sacc, 0, 0, 0);

      // ---- V frags: g = ks*4 + khalf*2 + dblk ----
      bf16x8 vf00 = *(const bf16x8*)(Kc + 8192 + (ks*4 + 0)*1024 + (lin2 ^ EG[ks*4 + 0]));
      bf16x8 vf01 = *(const bf16x8*)(Kc + 8192 + (ks*4 + 1)*1024 + (lin2 ^ EG[ks*4 + 1]));
      bf16x8 vf10 = *(const bf16x8*)(Kc + 8192 + (ks*4 + 2)*1024 + (lin2 ^ EG[ks*4 + 2]));
      bf16x8 vf11 = *(const bf16x8*)(Kc + 8192 + (ks*4 + 3)*1024 + (lin2 ^ EG[ks*4 + 3]));

      // ---- softmax numerator: p = 2^sacc; 4 independent partial sums ----
      float p[16];
      #pragma unroll
      for(int r=0;r<16;r++) p[r] = EXP2F(sacc[r]);
      #pragma unroll
      for(int r=0;r<16;r+=4){
        lp0 += p[r]; lp1 += p[r+1]; lp2 += p[r+2]; lp3 += p[r+3];
      }

      // ---- P -> A-frags in-register (verified v7 pipeline) ----
      unsigned int d0 = cvtpk_bf16(p[0],  p[1]);
      unsigned int d1 = cvtpk_bf16(p[2],  p[3]);
      unsigned int d2 = cvtpk_bf16(p[4],  p[5]);
      unsigned int d3 = cvtpk_bf16(p[6],  p[7]);
      unsigned int d4 = cvtpk_bf16(p[8],  p[9]);
      unsigned int d5 = cvtpk_bf16(p[10], p[11]);
      unsigned int d6 = cvtpk_bf16(p[12], p[13]);
      unsigned int d7 = cvtpk_bf16(p[14], p[15]);
      plswap32(d0, d2); plswap32(d1, d3);          // chunk0: k = 8hi + 0..7
      plswap32(d4, d6); plswap32(d5, d7);          // chunk1: k = 16 + 8hi + 0..7
      unsigned int c0w[4] = {d0, d1, d2, d3};
      unsigned int c1w[4] = {d4, d5, d6, d7};
      bf16x8 pa0 = *(const bf16x8*)c0w;            // P[q=l31][k = hi*8+0..7]
      bf16x8 pa1 = *(const bf16x8*)c1w;            // P[q=l31][k = 16+hi*8+0..7]

      // ---- PV: O[32q x 64d] accumulate ----
      oacc0 = __builtin_amdgcn_mfma_f32_32x32x16_bf16(pa0, vf00, oacc0, 0, 0, 0);
      oacc1 = __builtin_amdgcn_mfma_f32_32x32x16_bf16(pa0, vf01, oacc1, 0, 0, 0);
      oacc0 = __builtin_amdgcn_mfma_f32_32x32x16_bf16(pa1, vf10, oacc0, 0, 0, 0);
      oacc1 = __builtin_amdgcn_mfma_f32_32x32x16_bf16(pa1, vf11, oacc1, 0, 0, 0);
    }

    if(it + 1 < 32){               // write staged regs to the other buffer
      char* Wn = (char*)KV[cur ^ 1];
      *(uint4*)(Wn + kwoff[0]) = ka0;
      *(uint4*)(Wn + kwoff[1]) = ka1;
      *(uint4*)(Wn + vwoff[0]) = va0;
      *(uint4*)(Wn + vwoff[1]) = va1;
    }
    cur ^= 1;
  }

  // ---- l: combine partials + hi-halves (lane l, l^32 share q=l31) ----
  float lpart = (lp0 + lp1) + (lp2 + lp3);
  lpart += __shfl_xor(lpart, 32, 64);
  if(lane < 32) linv_lds[w*32 + l31] = 1.0f / lpart;
  __syncthreads();

  // ---- epilogue: O row q=(r&3)+8(r>>2)+4hi, col d = dblk*32 + l31 ----
  #pragma unroll
  for(int r=0;r<16;r++){
    int qrow = (r&3) + 8*(r>>2) + 4*hi;
    float li = linv_lds[w*32 + qrow];
    unsigned short* row = Qg + (size_t)qrow*2304;
    row[l31]      = fast2bf(oacc0[r] * li);
    row[32 + l31] = fast2bf(oacc1[r] * li);
  }
}

// ---------------------------------------------------------------------------
extern "C" void kernel_launch(void* const* d_in, const int* in_sizes, int n_in,
                              void* d_out, int out_size, void* d_ws, size_t ws_size,
                              hipStream_t stream){
  const float* x      = (const float*)d_in[0];  // [8192][768]
  const float* w_qkv  = (const float*)d_in[1];  // [768][2304]
  const float* b_qkv  = (const float*)d_in[2];  // [2304]
  const float* w_proj = (const float*)d_in[3];  // [768][768]
  const float* b_proj = (const float*)d_in[4];  // [768]
  float* out = (float*)d_out;                   // [8192][768]

  unsigned short* xb      = (unsigned short*)d_ws;                   // [8192][768]
  unsigned short* Wt_qkv  = xb      + (size_t)8192*768;              // [2304][768]
  unsigned short* Wt_proj = Wt_qkv  + (size_t)2304*768;              // [768][768]
  unsigned short* qkvb    = Wt_proj + (size_t)768*768;               // [8192][2304]
  unsigned short* VT      = xb;   // aliases xb: xb dead after gemm1

  f32_to_bf16<<<(8192*768)/1024, 256, 0, stream>>>(x, xb, 8192*768);
  transpose_f32_bf16<<<dim3(72, 24), dim3(32, 8), 0, stream>>>(w_qkv,  Wt_qkv,  768, 2304);
  transpose_f32_bf16<<<dim3(24, 24), dim3(32, 8), 0, stream>>>(w_proj, Wt_proj, 768, 768);

  gemm_bt<unsigned short><<<dim3(2304/128, 8192/128), 256, 0, stream>>>(
      xb, Wt_qkv, b_qkv, qkvb, 8192, 2304, 768, 768);

  transpose_v<<<dim3(32, 48), 256, 0, stream>>>(qkvb, VT);

  attn_mfma<<<768, 256, 0, stream>>>(qkvb, VT);

  gemm_bt<float><<<dim3(768/128, 8192/128), 256, 0, stream>>>(
      qkvb, Wt_proj, b_proj, out, 8192, 768, 768, 2304);
}

// Round 7
// 219.301 us; speedup vs baseline: 1.0074x; 1.0074x over previous
//
#include <hip/hip_runtime.h>
#include <stdint.h>
#include <stddef.h>

// ---------------------------------------------------------------------------
// B=4, N=2048, D=768, H=12, HD=64. BN=8192.
// I/O fp32; internal bf16 MFMA + fp32 accum.
// qkv hidden [8192][2304] bf16 (Q 0..767 | K 768..1535 | V 1536..2303).
// V also materialized transposed: VT[(b*12+h)*64+d][2048 j] (aliases xb).
// Attention overwrites the Q region in place with merged-head output.
// attn v10 (REVERT of failed v11; v10 verified passing, 0 bank conflicts):
// fragment-order LDS + coalesced reg-staging + T14 split.
// gemm_bt v3: + XCD-clustered bijective block remap (T1): each XCD gets a
// contiguous logical range = 8 m-rows x all n-tiles -> panel reuse in its L2.
// (Round 6 was an infra failure — this source is the unchanged resubmission.)
// ---------------------------------------------------------------------------

typedef __bf16 bf16x8 __attribute__((ext_vector_type(8)));
typedef float  f32x4  __attribute__((ext_vector_type(4)));
typedef float  f32x16 __attribute__((ext_vector_type(16)));
typedef unsigned int u32x2 __attribute__((ext_vector_type(2)));

__device__ __forceinline__ float bf2f(unsigned short u){
  union { unsigned int i; float f; } x; x.i = ((unsigned int)u) << 16; return x.f;
}
// round-half-up bf16
__device__ __forceinline__ unsigned short fast2bf(float f){
  union { float f; unsigned int i; } x; x.f = f;
  return (unsigned short)((x.i + 0x8000u) >> 16);
}
// single-instruction packed fp32->bf16 pair (RNE)
__device__ __forceinline__ unsigned int cvtpk_bf16(float lo, float hi){
  unsigned int r;
  asm("v_cvt_pk_bf16_f32 %0, %1, %2" : "=v"(r) : "v"(lo), "v"(hi));
  return r;
}
// v_permlane32_swap_b32: a' = {a.lo32lanes, b.lo32lanes}, b' = {a.hi, b.hi}
__device__ __forceinline__ void plswap32(unsigned int &a, unsigned int &b){
#if __has_builtin(__builtin_amdgcn_permlane32_swap)
  u32x2 r = __builtin_amdgcn_permlane32_swap(a, b, false, false);
  a = r.x; b = r.y;
#else
  asm volatile("v_permlane32_swap_b32 %0, %1" : "+v"(a), "+v"(b));
#endif
}

#if __has_builtin(__builtin_amdgcn_exp2f)
  #define EXP2F(x) __builtin_amdgcn_exp2f(x)
#else
  #define EXP2F(x) exp2f(x)
#endif

// async global->LDS, 16B per lane; LDS dest = wave-uniform base + lane*16.
#define GLD16(gp, lp) __builtin_amdgcn_global_load_lds( \
  (__attribute__((address_space(1))) void*)(uintptr_t)(gp), \
  (__attribute__((address_space(3))) void*)(unsigned int)(uintptr_t)(lp), 16, 0, 0)

// ---------------------------------------------------------------------------
__global__ void f32_to_bf16(const float* __restrict__ in,
                            unsigned short* __restrict__ out, int n){
  int i = (blockIdx.x * 256 + threadIdx.x) * 4;
  if(i < n){
    float4 v = *(const float4*)(in + i);
    ushort4 o;
    o.x = fast2bf(v.x); o.y = fast2bf(v.y); o.z = fast2bf(v.z); o.w = fast2bf(v.w);
    *(ushort4*)(out + i) = o;
  }
}

// ---------------------------------------------------------------------------
__global__ void transpose_f32_bf16(const float* __restrict__ W,
                                   unsigned short* __restrict__ Wt, int K, int N){
  __shared__ float tile[32][33];
  int n0 = blockIdx.x * 32, k0 = blockIdx.y * 32;
  int tx = threadIdx.x, ty = threadIdx.y;   // (32,8)
  for(int i = ty; i < 32; i += 8) tile[i][tx] = W[(size_t)(k0 + i) * N + (n0 + tx)];
  __syncthreads();
  for(int i = ty; i < 32; i += 8) Wt[(size_t)(n0 + i) * K + (k0 + tx)] = fast2bf(tile[tx][i]);
}

// ---------------------------------------------------------------------------
// V transpose: VT[(b*12+h)*64 + d][j] = qkv[b*2048+j][1536 + h*64 + d]
// ---------------------------------------------------------------------------
__global__ __launch_bounds__(256) void transpose_v(const unsigned short* __restrict__ qkv,
                                                   unsigned short* __restrict__ VT){
  __shared__ __align__(16) unsigned short Ts[64*72];
  const int t  = threadIdx.x;
  const int jt = blockIdx.x;        // 0..31
  const int bh = blockIdx.y;        // 0..47
  const int b = bh / 12, h = bh - b*12;
  const unsigned short* src = qkv + (size_t)(b*2048 + jt*64)*2304 + 1536 + h*64;
  #pragma unroll
  for(int c = t; c < 512; c += 256){
    int j = c >> 3, d0 = (c & 7) * 8;
    *(uint4*)&Ts[j*72 + d0] = *(const uint4*)(src + (size_t)j*2304 + d0);
  }
  __syncthreads();
  unsigned short* dst = VT + (size_t)bh*64*2048 + jt*64;
  #pragma unroll
  for(int c = t; c < 512; c += 256){
    int d = c >> 3, j0 = (c & 7) * 8;
    ushort4 lo, hi;
    lo.x = Ts[(j0+0)*72 + d]; lo.y = Ts[(j0+1)*72 + d];
    lo.z = Ts[(j0+2)*72 + d]; lo.w = Ts[(j0+3)*72 + d];
    hi.x = Ts[(j0+4)*72 + d]; hi.y = Ts[(j0+5)*72 + d];
    hi.z = Ts[(j0+6)*72 + d]; hi.w = Ts[(j0+7)*72 + d];
    *(ushort4*)(dst + (size_t)d*2048 + j0)     = lo;
    *(ushort4*)(dst + (size_t)d*2048 + j0 + 4) = hi;
  }
}

// ---------------------------------------------------------------------------
// MFMA GEMM-BT v3: C = A*Bt^T + bias. 128x128 tile, BK=32, double-buffered
// global_load_lds + XCD-clustered block remap (T1).
// ---------------------------------------------------------------------------
template<typename OT>
__global__ __launch_bounds__(256) void gemm_bt(const unsigned short* __restrict__ A,
                                               const unsigned short* __restrict__ Bt,
                                               const float* __restrict__ bias,
                                               OT* __restrict__ C,
                                               int M, int N, int K, int lda){
  __shared__ __align__(16) unsigned short As[2][128*32];
  __shared__ __align__(16) unsigned short Bs[2][128*32];
  const int tid  = threadIdx.x;
  const int lane = tid & 63, w = tid >> 6;

  // XCD-clustered bijective remap (T1): HW ids round-robin across 8 XCDs;
  // map so each XCD owns a contiguous logical range (8 m-rows x all n-tiles
  // for our grids) -> A/B panel reuse lands in that XCD's private L2.
  const int nwg = gridDim.x * gridDim.y;
  int bid = blockIdx.y * gridDim.x + blockIdx.x;
  if((nwg & 7) == 0){
    const int cpx = nwg >> 3;
    bid = (bid & 7) * cpx + (bid >> 3);
  }
  const int m0 = (bid / gridDim.x) * 128;
  const int n0 = (bid % gridDim.x) * 128;

  f32x4 acc[4][4];
  #pragma unroll
  for(int i=0;i<4;i++)
    #pragma unroll
    for(int j=0;j<4;j++) acc[i][j] = (f32x4){0.f,0.f,0.f,0.f};

  const int c0 = w*64 + lane, c1 = c0 + 256;
  const unsigned short* Ag0 = A  + (size_t)(m0 + (c0>>2)) * lda + (c0&3)*8;
  const unsigned short* Ag1 = A  + (size_t)(m0 + (c1>>2)) * lda + (c1&3)*8;
  const unsigned short* Bg0 = Bt + (size_t)(n0 + (c0>>2)) * K   + (c0&3)*8;
  const unsigned short* Bg1 = Bt + (size_t)(n0 + (c1>>2)) * K   + (c1&3)*8;

  const int wm = w & 1, wn = w >> 1;
  const int quad = lane >> 4, l15 = lane & 15;

  // prologue: stage tile 0 into buffer 0
  GLD16(Ag0, As[0] +        w*512);
  GLD16(Ag1, As[0] + 2048 + w*512);
  GLD16(Bg0, Bs[0] +        w*512);
  GLD16(Bg1, Bs[0] + 2048 + w*512);

  int cur = 0;
  for(int kt = 0; kt < K; kt += 32){
    __syncthreads();               // drains GLD16(cur) for all waves
    if(kt + 32 < K){               // issue next tile into the other buffer
      int nx = cur ^ 1;
      GLD16(Ag0 + kt + 32, As[nx] +        w*512);
      GLD16(Ag1 + kt + 32, As[nx] + 2048 + w*512);
      GLD16(Bg0 + kt + 32, Bs[nx] +        w*512);
      GLD16(Bg1 + kt + 32, Bs[nx] + 2048 + w*512);
    }

    bf16x8 af[4], bfr[4];
    #pragma unroll
    for(int mt=0;mt<4;mt++) af[mt]  = *(const bf16x8*)&As[cur][(wm*64 + mt*16 + l15)*32 + quad*8];
    #pragma unroll
    for(int nt=0;nt<4;nt++) bfr[nt] = *(const bf16x8*)&Bs[cur][(wn*64 + nt*16 + l15)*32 + quad*8];
    #pragma unroll
    for(int mt=0;mt<4;mt++)
      #pragma unroll
      for(int nt=0;nt<4;nt++)
        acc[mt][nt] = __builtin_amdgcn_mfma_f32_16x16x32_bf16(af[mt], bfr[nt], acc[mt][nt], 0, 0, 0);
    cur ^= 1;
  }

  // epilogue: C/D layout col=lane&15, row=quad*4+reg
  #pragma unroll
  for(int nt=0;nt<4;nt++){
    int col = n0 + wn*64 + nt*16 + l15;
    float bv = bias[col];
    #pragma unroll
    for(int mt=0;mt<4;mt++){
      int row0 = m0 + wm*64 + mt*16 + quad*4;
      #pragma unroll
      for(int i=0;i<4;i++){
        float v = acc[mt][nt][i] + bv;
        if constexpr (sizeof(OT) == 2)
          C[(size_t)(row0 + i) * N + col] = (OT)fast2bf(v);
        else
          C[(size_t)(row0 + i) * N + col] = (OT)v;
      }
    }
  }
}

// ---------------------------------------------------------------------------
// MFMA flash attention v10 — frag-order LDS, coalesced reg-staging.
// (verified passing in round 4; reverted unchanged after v11's failure)
//
// Block = 256 threads = 4 waves; wave w owns q-rows q0 = bx*128 + w*32.
// 1-D grid 768 blocks, XCD-clustered remap (16 blocks sharing (b,h) -> 1 XCD).
//
// LDS (per 64-k tile, double-buffered): KV[buf] = K 8 groups x 1KB | V 8 x 1KB.
//   Frag slot (g, sl): the 16B lane sl reads for fragment-group g.
//   Physical slot-lane = sl ^ p,  p(g,hi) = (((g&3)<<1)|hi) ^ ((g>>2)<<1), hi=sl>>5.
//   Reads:  addr = g*1024 + (lane*16 ^ hi*16 ^ e(g)*32), e(g)=(g&3)^(g>>2):
//           within-128B-stripe permutation of linear -> 0 conflicts.
//   Writes: lane holds row w*8+(lane>>3) (+32L), chunk c8=lane&7 from a
//           coalesced b128 global load (8 rows x 128B/instr); each octet's 8
//           dests hit 8 distinct bank groups -> 0 conflicts.
// T14: global loads for tile n+1 issue at top of tile n's compute; ds_writes
// land after compute, before the single per-tile barrier.
// Per 32-k step: S^T = mfma(K,Q) x4 (q lane-local), p=exp2 (4 indep l-accums),
// P-frags via 8x cvt_pk_bf16 + 4x permlane32_swap, O += mfma(P,V) x4.
// ---------------------------------------------------------------------------
__global__ __launch_bounds__(256, 3) void attn_mfma(unsigned short* __restrict__ qkv,
                                                    const unsigned short* __restrict__ VT){
  __shared__ __align__(16) unsigned short KV[2][8192];   // 16KB per buffer: K|V
  __shared__ float linv_lds[4*32];

  const int t    = threadIdx.x;
  const int lane = t & 63, w = t >> 6;
  const int l31  = lane & 31, hi = lane >> 5;

  // XCD-clustered bijective remap: 768 % 8 == 0.
  const int bid = blockIdx.x;
  const int wg  = (bid & 7) * 96 + (bid >> 3);
  const int b   = wg / 192;                   // 16*12 = 192
  const int rem = wg - b * 192;
  const int h   = rem >> 4;
  const int bx  = rem & 15;
  const int q0  = bx * 128 + w * 32;

  unsigned short* Qg = qkv + (size_t)(b*2048 + q0)*2304 + h*64;

  // ---- Q B-frags: qf[c] = Q[q=l31][d = c*16 + hi*8 + 0..7], pre-scaled ----
  const float QSCALE = 0.125f * 1.4426950408889634f;
  bf16x8 qf[4];
  #pragma unroll
  for(int c=0;c<4;c++){
    uint4 raw = *(const uint4*)(Qg + (size_t)l31*2304 + c*16 + hi*8);
    const unsigned short* rp = (const unsigned short*)&raw;
    unsigned short o[8];
    #pragma unroll
    for(int e=0;e<8;e++) o[e] = fast2bf(bf2f(rp[e]) * QSCALE);
    qf[c] = *(const bf16x8*)o;
  }

  f32x16 oacc0, oacc1;
  #pragma unroll
  for(int i=0;i<16;i++){ oacc0[i] = 0.f; oacc1[i] = 0.f; }
  float lp0=0.f, lp1=0.f, lp2=0.f, lp3=0.f;

  // ---- staging geometry: lane loads row w*8+r8 (+32L), 16B chunk c8 ----
  const int r8 = lane >> 3, c8 = lane & 7;
  const unsigned short* gK = qkv + (size_t)(b*2048)*2304 + 768 + h*64
                           + (size_t)(w*8 + r8)*2304 + c8*8;
  const unsigned short* gV = VT + (size_t)(b*12 + h)*64*2048
                           + (size_t)(w*8 + r8)*2048 + c8*8;

  // ds_write byte offsets (lane-constant). K: g=L*4+(c8>>1), p=c8^(L<<1).
  // V: g=(c8>>2)*4+((c8>>1)&1)*2+L, p=(((g&3)<<1)|(c8&1))^((g>>2)<<1).
  int kwoff[2], vwoff[2];
  #pragma unroll
  for(int L=0; L<2; ++L){
    int sl = w*8 + r8 + 32*(c8&1);
    kwoff[L] = (L*4 + (c8>>1))*1024 + ((sl ^ (c8 ^ (L<<1))) * 16);
    int gVg  = (c8>>2)*4 + ((c8>>1)&1)*2 + L;
    int pV   = ((((gVg&3)<<1) | (c8&1)) ^ ((gVg>>2)<<1));
    vwoff[L] = 8192 + gVg*1024 + ((sl ^ pV) * 16);
  }

  // read base: lane*16 ^ hi*16; per-group XOR e(g)*32, e(g)=(g&3)^(g>>2)
  const int lin2 = (lane*16) ^ (hi*16);
  const int EG[8] = {0, 32, 64, 96, 32, 0, 96, 64};

  // ---- prologue: load + write tile 0 into buffer 0 ----
  uint4 ka0 = *(const uint4*)(gK);
  uint4 ka1 = *(const uint4*)(gK + (size_t)32*2304);
  uint4 va0 = *(const uint4*)(gV);
  uint4 va1 = *(const uint4*)(gV + (size_t)32*2048);
  {
    char* W0 = (char*)KV[0];
    *(uint4*)(W0 + kwoff[0]) = ka0;
    *(uint4*)(W0 + kwoff[1]) = ka1;
    *(uint4*)(W0 + vwoff[0]) = va0;
    *(uint4*)(W0 + vwoff[1]) = va1;
  }

  int cur = 0;
  #pragma unroll 1
  for(int it = 0; it < 32; ++it){
    __syncthreads();               // KV[cur] fully written, safe to read
    if(it + 1 < 32){               // issue next tile's coalesced loads now
      gK += (size_t)64*2304;
      gV += 64;
      ka0 = *(const uint4*)(gK);
      ka1 = *(const uint4*)(gK + (size_t)32*2304);
      va0 = *(const uint4*)(gV);
      va1 = *(const uint4*)(gV + (size_t)32*2048);
    }
    const char* Kc = (const char*)KV[cur];

    #pragma unroll
    for(int ks = 0; ks < 2; ++ks){
      // ---- K frags (0-conflict permuted-linear reads) ----
      bf16x8 kf0 = *(const bf16x8*)(Kc + (ks*4 + 0)*1024 + (lin2 ^ EG[ks*4 + 0]));
      bf16x8 kf1 = *(const bf16x8*)(Kc + (ks*4 + 1)*1024 + (lin2 ^ EG[ks*4 + 1]));
      bf16x8 kf2 = *(const bf16x8*)(Kc + (ks*4 + 2)*1024 + (lin2 ^ EG[ks*4 + 2]));
      bf16x8 kf3 = *(const bf16x8*)(Kc + (ks*4 + 3)*1024 + (lin2 ^ EG[ks*4 + 3]));

      // ---- S^T tile: 32k x 32q ----
      f32x16 sacc;
      #pragma unroll
      for(int i=0;i<16;i++) sacc[i] = 0.f;
      sacc = __builtin_amdgcn_mfma_f32_32x32x16_bf16(kf0, qf[0], sacc, 0, 0, 0);
      sacc = __builtin_amdgcn_mfma_f32_32x32x16_bf16(kf1, qf[1], sacc, 0, 0, 0);
      sacc = __builtin_amdgcn_mfma_f32_32x32x16_bf16(kf2, qf[2], sacc, 0, 0, 0);
      sacc = __builtin_amdgcn_mfma_f32_32x32x16_bf16(kf3, qf[3], sacc, 0, 0, 0);

      // ---- V frags: g = ks*4 + khalf*2 + dblk ----
      bf16x8 vf00 = *(const bf16x8*)(Kc + 8192 + (ks*4 + 0)*1024 + (lin2 ^ EG[ks*4 + 0]));
      bf16x8 vf01 = *(const bf16x8*)(Kc + 8192 + (ks*4 + 1)*1024 + (lin2 ^ EG[ks*4 + 1]));
      bf16x8 vf10 = *(const bf16x8*)(Kc + 8192 + (ks*4 + 2)*1024 + (lin2 ^ EG[ks*4 + 2]));
      bf16x8 vf11 = *(const bf16x8*)(Kc + 8192 + (ks*4 + 3)*1024 + (lin2 ^ EG[ks*4 + 3]));

      // ---- softmax numerator: p = 2^sacc; 4 independent partial sums ----
      float p[16];
      #pragma unroll
      for(int r=0;r<16;r++) p[r] = EXP2F(sacc[r]);
      #pragma unroll
      for(int r=0;r<16;r+=4){
        lp0 += p[r]; lp1 += p[r+1]; lp2 += p[r+2]; lp3 += p[r+3];
      }

      // ---- P -> A-frags in-register (verified v7 pipeline) ----
      unsigned int d0 = cvtpk_bf16(p[0],  p[1]);
      unsigned int d1 = cvtpk_bf16(p[2],  p[3]);
      unsigned int d2 = cvtpk_bf16(p[4],  p[5]);
      unsigned int d3 = cvtpk_bf16(p[6],  p[7]);
      unsigned int d4 = cvtpk_bf16(p[8],  p[9]);
      unsigned int d5 = cvtpk_bf16(p[10], p[11]);
      unsigned int d6 = cvtpk_bf16(p[12], p[13]);
      unsigned int d7 = cvtpk_bf16(p[14], p[15]);
      plswap32(d0, d2); plswap32(d1, d3);          // chunk0: k = 8hi + 0..7
      plswap32(d4, d6); plswap32(d5, d7);          // chunk1: k = 16 + 8hi + 0..7
      unsigned int c0w[4] = {d0, d1, d2, d3};
      unsigned int c1w[4] = {d4, d5, d6, d7};
      bf16x8 pa0 = *(const bf16x8*)c0w;            // P[q=l31][k = hi*8+0..7]
      bf16x8 pa1 = *(const bf16x8*)c1w;            // P[q=l31][k = 16+hi*8+0..7]

      // ---- PV: O[32q x 64d] accumulate ----
      oacc0 = __builtin_amdgcn_mfma_f32_32x32x16_bf16(pa0, vf00, oacc0, 0, 0, 0);
      oacc1 = __builtin_amdgcn_mfma_f32_32x32x16_bf16(pa0, vf01, oacc1, 0, 0, 0);
      oacc0 = __builtin_amdgcn_mfma_f32_32x32x16_bf16(pa1, vf10, oacc0, 0, 0, 0);
      oacc1 = __builtin_amdgcn_mfma_f32_32x32x16_bf16(pa1, vf11, oacc1, 0, 0, 0);
    }

    if(it + 1 < 32){               // write staged regs to the other buffer
      char* Wn = (char*)KV[cur ^ 1];
      *(uint4*)(Wn + kwoff[0]) = ka0;
      *(uint4*)(Wn + kwoff[1]) = ka1;
      *(uint4*)(Wn + vwoff[0]) = va0;
      *(uint4*)(Wn + vwoff[1]) = va1;
    }
    cur ^= 1;
  }

  // ---- l: combine partials + hi-halves (lane l, l^32 share q=l31) ----
  float lpart = (lp0 + lp1) + (lp2 + lp3);
  lpart += __shfl_xor(lpart, 32, 64);
  if(lane < 32) linv_lds[w*32 + l31] = 1.0f / lpart;
  __syncthreads();

  // ---- epilogue: O row q=(r&3)+8(r>>2)+4hi, col d = dblk*32 + l31 ----
  #pragma unroll
  for(int r=0;r<16;r++){
    int qrow = (r&3) + 8*(r>>2) + 4*hi;
    float li = linv_lds[w*32 + qrow];
    unsigned short* row = Qg + (size_t)qrow*2304;
    row[l31]      = fast2bf(oacc0[r] * li);
    row[32 + l31] = fast2bf(oacc1[r] * li);
  }
}

// ---------------------------------------------------------------------------
extern "C" void kernel_launch(void* const* d_in, const int* in_sizes, int n_in,
                              void* d_out, int out_size, void* d_ws, size_t ws_size,
                              hipStream_t stream){
  const float* x      = (const float*)d_in[0];  // [8192][768]
  const float* w_qkv  = (const float*)d_in[1];  // [768][2304]
  const float* b_qkv  = (const float*)d_in[2];  // [2304]
  const float* w_proj = (const float*)d_in[3];  // [768][768]
  const float* b_proj = (const float*)d_in[4];  // [768]
  float* out = (float*)d_out;                   // [8192][768]

  unsigned short* xb      = (unsigned short*)d_ws;                   // [8192][768]
  unsigned short* Wt_qkv  = xb      + (size_t)8192*768;              // [2304][768]
  unsigned short* Wt_proj = Wt_qkv  + (size_t)2304*768;              // [768][768]
  unsigned short* qkvb    = Wt_proj + (size_t)768*768;               // [8192][2304]
  unsigned short* VT      = xb;   // aliases xb: xb dead after gemm1

  f32_to_bf16<<<(8192*768)/1024, 256, 0, stream>>>(x, xb, 8192*768);
  transpose_f32_bf16<<<dim3(72, 24), dim3(32, 8), 0, stream>>>(w_qkv,  Wt_qkv,  768, 2304);
  transpose_f32_bf16<<<dim3(24, 24), dim3(32, 8), 0, stream>>>(w_proj, Wt_proj, 768, 768);

  gemm_bt<unsigned short><<<dim3(2304/128, 8192/128), 256, 0, stream>>>(
      xb, Wt_qkv, b_qkv, qkvb, 8192, 2304, 768, 768);

  transpose_v<<<dim3(32, 48), 256, 0, stream>>>(qkvb, VT);

  attn_mfma<<<768, 256, 0, stream>>>(qkvb, VT);

  gemm_bt<float><<<dim3(768/128, 8192/128), 256, 0, stream>>>(
      qkvb, Wt_proj, b_proj, out, 8192, 768, 768, 2304);
}

// Round 8
// 211.387 us; speedup vs baseline: 1.0452x; 1.0374x over previous
//
#include <hip/hip_runtime.h>
#include <stdint.h>
#include <stddef.h>

// ---------------------------------------------------------------------------
// B=4, N=2048, D=768, H=12, HD=64. BN=8192.
// I/O fp32; internal bf16 MFMA + fp32 accum.
// qkv hidden [8192][2304] bf16 (Q 0..767 | K 768..1535 | V 1536..2303).
// V also materialized transposed: VT[(b*12+h)*64+d][2048 j] (aliases xb).
// Attention overwrites the Q region in place with merged-head output.
//
// Round-8 consolidation:
//  * attn v8 VERBATIM (round-2 source): best measured attn (60.5us). GLD16
//    direct-to-LDS staging (async, no VGPR round-trip); its 6.3M bank
//    conflicts cost less than v10's reg-staging VALU/ds_write overhead
//    (v10 measured 62.6-68.6us). Counter-chasing reverted; clock wins.
//  * gemm_bt v3 with T1 XCD swizzle (measured ~6us gain on non-attn total).
//  * prep kernels fused into ONE dispatch (f32->bf16 + both W transposes)
//    via block-range dispatch: removes 2 launch gaps.
// ---------------------------------------------------------------------------

typedef __bf16 bf16x8 __attribute__((ext_vector_type(8)));
typedef float  f32x4  __attribute__((ext_vector_type(4)));
typedef float  f32x16 __attribute__((ext_vector_type(16)));
typedef unsigned int u32x2 __attribute__((ext_vector_type(2)));

__device__ __forceinline__ float bf2f(unsigned short u){
  union { unsigned int i; float f; } x; x.i = ((unsigned int)u) << 16; return x.f;
}
// round-half-up bf16
__device__ __forceinline__ unsigned short fast2bf(float f){
  union { float f; unsigned int i; } x; x.f = f;
  return (unsigned short)((x.i + 0x8000u) >> 16);
}
// single-instruction packed fp32->bf16 pair (RNE)
__device__ __forceinline__ unsigned int cvtpk_bf16(float lo, float hi){
  unsigned int r;
  asm("v_cvt_pk_bf16_f32 %0, %1, %2" : "=v"(r) : "v"(lo), "v"(hi));
  return r;
}
// v_permlane32_swap_b32: a' = {a.lo32lanes, b.lo32lanes}, b' = {a.hi, b.hi}
__device__ __forceinline__ void plswap32(unsigned int &a, unsigned int &b){
#if __has_builtin(__builtin_amdgcn_permlane32_swap)
  u32x2 r = __builtin_amdgcn_permlane32_swap(a, b, false, false);
  a = r.x; b = r.y;
#else
  asm volatile("v_permlane32_swap_b32 %0, %1" : "+v"(a), "+v"(b));
#endif
}

#if __has_builtin(__builtin_amdgcn_exp2f)
  #define EXP2F(x) __builtin_amdgcn_exp2f(x)
#else
  #define EXP2F(x) exp2f(x)
#endif

// async global->LDS, 16B per lane; LDS dest = wave-uniform base + lane*16.
#define GLD16(gp, lp) __builtin_amdgcn_global_load_lds( \
  (__attribute__((address_space(1))) void*)(uintptr_t)(gp), \
  (__attribute__((address_space(3))) void*)(unsigned int)(uintptr_t)(lp), 16, 0, 0)

// ---------------------------------------------------------------------------
// Fused prep: blocks [0,6144) = f32->bf16 of x; [6144,7872) = w_qkv transpose;
// [7872,8448) = w_proj transpose. Branch is block-uniform.
// ---------------------------------------------------------------------------
__global__ __launch_bounds__(256) void prep_fused(const float* __restrict__ x,
                                                  unsigned short* __restrict__ xb,
                                                  const float* __restrict__ w_qkv,
                                                  unsigned short* __restrict__ Wt_qkv,
                                                  const float* __restrict__ w_proj,
                                                  unsigned short* __restrict__ Wt_proj){
  __shared__ float tile[32][33];
  const int bid = blockIdx.x;
  if(bid < 6144){
    int i = (bid * 256 + threadIdx.x) * 4;       // 8192*768 = 6144*1024
    float4 v = *(const float4*)(x + i);
    ushort4 o;
    o.x = fast2bf(v.x); o.y = fast2bf(v.y); o.z = fast2bf(v.z); o.w = fast2bf(v.w);
    *(ushort4*)(xb + i) = o;
    return;
  }
  const float* W; unsigned short* Wt; int K, N, n0, k0;
  if(bid < 7872){ int r = bid - 6144; W = w_qkv;  Wt = Wt_qkv;  K = 768; N = 2304;
                  n0 = (r % 72) * 32; k0 = (r / 72) * 32; }
  else          { int r = bid - 7872; W = w_proj; Wt = Wt_proj; K = 768; N = 768;
                  n0 = (r % 24) * 32; k0 = (r / 24) * 32; }
  const int tx = threadIdx.x & 31, ty = threadIdx.x >> 5;   // (32,8)
  for(int i = ty; i < 32; i += 8) tile[i][tx] = W[(size_t)(k0 + i) * N + (n0 + tx)];
  __syncthreads();
  for(int i = ty; i < 32; i += 8) Wt[(size_t)(n0 + i) * K + (k0 + tx)] = fast2bf(tile[tx][i]);
}

// ---------------------------------------------------------------------------
// V transpose: VT[(b*12+h)*64 + d][j] = qkv[b*2048+j][1536 + h*64 + d]
// ---------------------------------------------------------------------------
__global__ __launch_bounds__(256) void transpose_v(const unsigned short* __restrict__ qkv,
                                                   unsigned short* __restrict__ VT){
  __shared__ __align__(16) unsigned short Ts[64*72];
  const int t  = threadIdx.x;
  const int jt = blockIdx.x;        // 0..31
  const int bh = blockIdx.y;        // 0..47
  const int b = bh / 12, h = bh - b*12;
  const unsigned short* src = qkv + (size_t)(b*2048 + jt*64)*2304 + 1536 + h*64;
  #pragma unroll
  for(int c = t; c < 512; c += 256){
    int j = c >> 3, d0 = (c & 7) * 8;
    *(uint4*)&Ts[j*72 + d0] = *(const uint4*)(src + (size_t)j*2304 + d0);
  }
  __syncthreads();
  unsigned short* dst = VT + (size_t)bh*64*2048 + jt*64;
  #pragma unroll
  for(int c = t; c < 512; c += 256){
    int d = c >> 3, j0 = (c & 7) * 8;
    ushort4 lo, hi;
    lo.x = Ts[(j0+0)*72 + d]; lo.y = Ts[(j0+1)*72 + d];
    lo.z = Ts[(j0+2)*72 + d]; lo.w = Ts[(j0+3)*72 + d];
    hi.x = Ts[(j0+4)*72 + d]; hi.y = Ts[(j0+5)*72 + d];
    hi.z = Ts[(j0+6)*72 + d]; hi.w = Ts[(j0+7)*72 + d];
    *(ushort4*)(dst + (size_t)d*2048 + j0)     = lo;
    *(ushort4*)(dst + (size_t)d*2048 + j0 + 4) = hi;
  }
}

// ---------------------------------------------------------------------------
// MFMA GEMM-BT v3: C = A*Bt^T + bias. 128x128 tile, BK=32, double-buffered
// global_load_lds + XCD-clustered block remap (T1).
// ---------------------------------------------------------------------------
template<typename OT>
__global__ __launch_bounds__(256) void gemm_bt(const unsigned short* __restrict__ A,
                                               const unsigned short* __restrict__ Bt,
                                               const float* __restrict__ bias,
                                               OT* __restrict__ C,
                                               int M, int N, int K, int lda){
  __shared__ __align__(16) unsigned short As[2][128*32];
  __shared__ __align__(16) unsigned short Bs[2][128*32];
  const int tid  = threadIdx.x;
  const int lane = tid & 63, w = tid >> 6;

  // XCD-clustered bijective remap (T1).
  const int nwg = gridDim.x * gridDim.y;
  int bid = blockIdx.y * gridDim.x + blockIdx.x;
  if((nwg & 7) == 0){
    const int cpx = nwg >> 3;
    bid = (bid & 7) * cpx + (bid >> 3);
  }
  const int m0 = (bid / gridDim.x) * 128;
  const int n0 = (bid % gridDim.x) * 128;

  f32x4 acc[4][4];
  #pragma unroll
  for(int i=0;i<4;i++)
    #pragma unroll
    for(int j=0;j<4;j++) acc[i][j] = (f32x4){0.f,0.f,0.f,0.f};

  const int c0 = w*64 + lane, c1 = c0 + 256;
  const unsigned short* Ag0 = A  + (size_t)(m0 + (c0>>2)) * lda + (c0&3)*8;
  const unsigned short* Ag1 = A  + (size_t)(m0 + (c1>>2)) * lda + (c1&3)*8;
  const unsigned short* Bg0 = Bt + (size_t)(n0 + (c0>>2)) * K   + (c0&3)*8;
  const unsigned short* Bg1 = Bt + (size_t)(n0 + (c1>>2)) * K   + (c1&3)*8;

  const int wm = w & 1, wn = w >> 1;
  const int quad = lane >> 4, l15 = lane & 15;

  // prologue: stage tile 0 into buffer 0
  GLD16(Ag0, As[0] +        w*512);
  GLD16(Ag1, As[0] + 2048 + w*512);
  GLD16(Bg0, Bs[0] +        w*512);
  GLD16(Bg1, Bs[0] + 2048 + w*512);

  int cur = 0;
  for(int kt = 0; kt < K; kt += 32){
    __syncthreads();               // drains GLD16(cur) for all waves
    if(kt + 32 < K){               // issue next tile into the other buffer
      int nx = cur ^ 1;
      GLD16(Ag0 + kt + 32, As[nx] +        w*512);
      GLD16(Ag1 + kt + 32, As[nx] + 2048 + w*512);
      GLD16(Bg0 + kt + 32, Bs[nx] +        w*512);
      GLD16(Bg1 + kt + 32, Bs[nx] + 2048 + w*512);
    }

    bf16x8 af[4], bfr[4];
    #pragma unroll
    for(int mt=0;mt<4;mt++) af[mt]  = *(const bf16x8*)&As[cur][(wm*64 + mt*16 + l15)*32 + quad*8];
    #pragma unroll
    for(int nt=0;nt<4;nt++) bfr[nt] = *(const bf16x8*)&Bs[cur][(wn*64 + nt*16 + l15)*32 + quad*8];
    #pragma unroll
    for(int mt=0;mt<4;mt++)
      #pragma unroll
      for(int nt=0;nt<4;nt++)
        acc[mt][nt] = __builtin_amdgcn_mfma_f32_16x16x32_bf16(af[mt], bfr[nt], acc[mt][nt], 0, 0, 0);
    cur ^= 1;
  }

  // epilogue: C/D layout col=lane&15, row=quad*4+reg
  #pragma unroll
  for(int nt=0;nt<4;nt++){
    int col = n0 + wn*64 + nt*16 + l15;
    float bv = bias[col];
    #pragma unroll
    for(int mt=0;mt<4;mt++){
      int row0 = m0 + wm*64 + mt*16 + quad*4;
      #pragma unroll
      for(int i=0;i<4;i++){
        float v = acc[mt][nt][i] + bv;
        if constexpr (sizeof(OT) == 2)
          C[(size_t)(row0 + i) * N + col] = (OT)fast2bf(v);
        else
          C[(size_t)(row0 + i) * N + col] = (OT)v;
      }
    }
  }
}

// ---------------------------------------------------------------------------
// MFMA flash attention v8 (VERBATIM round-2 source — best measured: 60.5us).
// Wave-independent softmax, LDS-shared K/V tiles via direct global_load_lds.
//
// Block = 256 threads = 4 waves; wave w owns q-rows q0 = bx*128 + w*32.
// 1-D grid 768 blocks, XCD-clustered remap (blocks sharing (b,h) -> same XCD).
//
// K/V staged per 64-k tile into LDS (double-buffered, 32 KB):
//   tile row = k (K) or d (V), 64 rows x 128B. Stage via GLD16, 2 rounds per
//   wave per matrix (w*8+lane>>3 rows), SOURCE chunk pre-swizzled by
//   (lane&7)^(lane>>3)  ->  LDS[row][c] = M[row][c ^ (row&7)].
//   Frag ds_read_b128 at chunk (cc ^ (l31&7)).
// Per 32-k step (32x32x16 MFMAs, verified v7 math):
//   S^T = mfma(A=K,B=Q) -> q = lane&31 lane-local; p=exp2; l += p (scalar);
//   P-frags via 8x cvt_pk_bf16 + 4x permlane32_swap; O += mfma(P,V) x4.
// One barrier per 64-k tile (drains next-tile GLD16, proven gemm_bt pattern).
// ---------------------------------------------------------------------------
__global__ __launch_bounds__(256, 3) void attn_mfma(unsigned short* __restrict__ qkv,
                                                    const unsigned short* __restrict__ VT){
  __shared__ __align__(16) unsigned short Ks[2][64*64];
  __shared__ __align__(16) unsigned short Vs[2][64*64];
  __shared__ float linv_lds[4*32];

  const int t    = threadIdx.x;
  const int lane = t & 63, w = t >> 6;
  const int l31  = lane & 31, hi = lane >> 5;
  const int sx   = l31 & 7;            // ds_read swizzle key (row&7)

  // XCD-clustered bijective remap: 768 % 8 == 0.
  const int bid = blockIdx.x;
  const int wg  = (bid & 7) * 96 + (bid >> 3);
  const int b   = wg / 192;                   // 16*12 = 192
  const int rem = wg - b * 192;
  const int h   = rem >> 4;
  const int bx  = rem & 15;
  const int q0  = bx * 128 + w * 32;

  unsigned short* Qg = qkv + (size_t)(b*2048 + q0)*2304 + h*64;

  // ---- Q B-frags: qf[c] = Q[q=l31][d = c*16 + hi*8 + 0..7], pre-scaled ----
  const float QSCALE = 0.125f * 1.4426950408889634f;
  bf16x8 qf[4];
  #pragma unroll
  for(int c=0;c<4;c++){
    uint4 raw = *(const uint4*)(Qg + (size_t)l31*2304 + c*16 + hi*8);
    const unsigned short* rp = (const unsigned short*)&raw;
    unsigned short o[8];
    #pragma unroll
    for(int e=0;e<8;e++) o[e] = fast2bf(bf2f(rp[e]) * QSCALE);
    qf[c] = *(const bf16x8*)o;
  }

  f32x16 oacc0, oacc1;
  #pragma unroll
  for(int i=0;i<16;i++){ oacc0[i] = 0.f; oacc1[i] = 0.f; }
  float lpart = 0.f;

  // ---- staging geometry: 2 GLD16 rounds/wave/matrix, rows w*8+(lane>>3) ----
  const int r8 = lane >> 3, c8 = lane & 7;
  const int scw = c8 ^ r8;                    // source chunk (row&7 == r8)
  const unsigned short* gK = qkv + (size_t)(b*2048)*2304 + 768 + h*64;   // +kt*2304
  const unsigned short* gV = VT + (size_t)(b*12 + h)*64*2048;            // +kt
  const size_t kOffA = (size_t)(w*8 + r8)*2304 + scw*8;
  const size_t kOffB = kOffA + (size_t)32*2304;
  const size_t vOffA = (size_t)(w*8 + r8)*2048 + scw*8;
  const size_t vOffB = vOffA + (size_t)32*2048;

  // prologue: stage tile 0 into buffer 0
  GLD16(gK + kOffA, Ks[0] +        w*512);
  GLD16(gK + kOffB, Ks[0] + 2048 + w*512);
  GLD16(gV + vOffA, Vs[0] +        w*512);
  GLD16(gV + vOffB, Vs[0] + 2048 + w*512);

  int cur = 0;
  #pragma unroll 1
  for(int it = 0; it < 32; ++it){
    __syncthreads();               // buf[cur] staged (drains GLD16) for all waves
    if(it + 1 < 32){               // stage next 64-k tile into other buffer
      int nx = cur ^ 1;
      gK += (size_t)64*2304;
      gV += 64;
      GLD16(gK + kOffA, Ks[nx] +        w*512);
      GLD16(gK + kOffB, Ks[nx] + 2048 + w*512);
      GLD16(gV + vOffA, Vs[nx] +        w*512);
      GLD16(gV + vOffB, Vs[nx] + 2048 + w*512);
    }
    const unsigned short* Kst = Ks[cur];
    const unsigned short* Vst = Vs[cur];

    #pragma unroll
    for(int ks = 0; ks < 2; ++ks){
      // ---- K frags: kf[c] = K[k = ks*32 + l31][d = c*16 + hi*8 + 0..7] ----
      bf16x8 kf[4];
      #pragma unroll
      for(int c=0;c<4;c++)
        kf[c] = *(const bf16x8*)&Kst[(ks*32 + l31)*64 + (((c*2 + hi) ^ sx) * 8)];

      // ---- S^T tile: 32k x 32q ----
      f32x16 sacc;
      #pragma unroll
      for(int i=0;i<16;i++) sacc[i] = 0.f;
      sacc = __builtin_amdgcn_mfma_f32_32x32x16_bf16(kf[0], qf[0], sacc, 0, 0, 0);
      sacc = __builtin_amdgcn_mfma_f32_32x32x16_bf16(kf[1], qf[1], sacc, 0, 0, 0);
      sacc = __builtin_amdgcn_mfma_f32_32x32x16_bf16(kf[2], qf[2], sacc, 0, 0, 0);
      sacc = __builtin_amdgcn_mfma_f32_32x32x16_bf16(kf[3], qf[3], sacc, 0, 0, 0);

      // ---- V frags (issued before exp; lgkm latency hides under VALU) ----
      // vf(khalf,dblk): V[k = ks*32 + khalf*16 + hi*8 + e][d = dblk*32 + l31]
      bf16x8 vf00 = *(const bf16x8*)&Vst[(     l31)*64 + (((ks*4 + 0 + hi) ^ sx) * 8)];
      bf16x8 vf01 = *(const bf16x8*)&Vst[(32 + l31)*64 + (((ks*4 + 0 + hi) ^ sx) * 8)];
      bf16x8 vf10 = *(const bf16x8*)&Vst[(     l31)*64 + (((ks*4 + 2 + hi) ^ sx) * 8)];
      bf16x8 vf11 = *(const bf16x8*)&Vst[(32 + l31)*64 + (((ks*4 + 2 + hi) ^ sx) * 8)];

      // ---- softmax numerator: p = 2^sacc; lane-local row sum ----
      float p[16];
      #pragma unroll
      for(int r=0;r<16;r++){ p[r] = EXP2F(sacc[r]); lpart += p[r]; }

      // ---- P -> A-frags in-register (verified v7 pipeline) ----
      unsigned int d0 = cvtpk_bf16(p[0],  p[1]);
      unsigned int d1 = cvtpk_bf16(p[2],  p[3]);
      unsigned int d2 = cvtpk_bf16(p[4],  p[5]);
      unsigned int d3 = cvtpk_bf16(p[6],  p[7]);
      unsigned int d4 = cvtpk_bf16(p[8],  p[9]);
      unsigned int d5 = cvtpk_bf16(p[10], p[11]);
      unsigned int d6 = cvtpk_bf16(p[12], p[13]);
      unsigned int d7 = cvtpk_bf16(p[14], p[15]);
      plswap32(d0, d2); plswap32(d1, d3);          // chunk0: k = 8hi + 0..7
      plswap32(d4, d6); plswap32(d5, d7);          // chunk1: k = 16 + 8hi + 0..7
      unsigned int c0w[4] = {d0, d1, d2, d3};
      unsigned int c1w[4] = {d4, d5, d6, d7};
      bf16x8 pa0 = *(const bf16x8*)c0w;            // P[q=l31][k = hi*8+0..7]
      bf16x8 pa1 = *(const bf16x8*)c1w;            // P[q=l31][k = 16+hi*8+0..7]

      // ---- PV: O[32q x 64d] accumulate ----
      oacc0 = __builtin_amdgcn_mfma_f32_32x32x16_bf16(pa0, vf00, oacc0, 0, 0, 0);
      oacc1 = __builtin_amdgcn_mfma_f32_32x32x16_bf16(pa0, vf01, oacc1, 0, 0, 0);
      oacc0 = __builtin_amdgcn_mfma_f32_32x32x16_bf16(pa1, vf10, oacc0, 0, 0, 0);
      oacc1 = __builtin_amdgcn_mfma_f32_32x32x16_bf16(pa1, vf11, oacc1, 0, 0, 0);
    }
    cur ^= 1;
  }

  // ---- l: combine hi-halves (lane l and l^32 share q=l31), broadcast 1/l ----
  lpart += __shfl_xor(lpart, 32, 64);
  if(lane < 32) linv_lds[w*32 + l31] = 1.0f / lpart;
  __syncthreads();

  // ---- epilogue: O row q=(r&3)+8(r>>2)+4hi, col d = dblk*32 + l31 ----
  #pragma unroll
  for(int r=0;r<16;r++){
    int qrow = (r&3) + 8*(r>>2) + 4*hi;
    float li = linv_lds[w*32 + qrow];
    unsigned short* row = Qg + (size_t)qrow*2304;
    row[l31]      = fast2bf(oacc0[r] * li);
    row[32 + l31] = fast2bf(oacc1[r] * li);
  }
}

// ---------------------------------------------------------------------------
extern "C" void kernel_launch(void* const* d_in, const int* in_sizes, int n_in,
                              void* d_out, int out_size, void* d_ws, size_t ws_size,
                              hipStream_t stream){
  const float* x      = (const float*)d_in[0];  // [8192][768]
  const float* w_qkv  = (const float*)d_in[1];  // [768][2304]
  const float* b_qkv  = (const float*)d_in[2];  // [2304]
  const float* w_proj = (const float*)d_in[3];  // [768][768]
  const float* b_proj = (const float*)d_in[4];  // [768]
  float* out = (float*)d_out;                   // [8192][768]

  unsigned short* xb      = (unsigned short*)d_ws;                   // [8192][768]
  unsigned short* Wt_qkv  = xb      + (size_t)8192*768;              // [2304][768]
  unsigned short* Wt_proj = Wt_qkv  + (size_t)2304*768;              // [768][768]
  unsigned short* qkvb    = Wt_proj + (size_t)768*768;               // [8192][2304]
  unsigned short* VT      = xb;   // aliases xb: xb dead after gemm1

  prep_fused<<<8448, 256, 0, stream>>>(x, xb, w_qkv, Wt_qkv, w_proj, Wt_proj);

  gemm_bt<unsigned short><<<dim3(2304/128, 8192/128), 256, 0, stream>>>(
      xb, Wt_qkv, b_qkv, qkvb, 8192, 2304, 768, 768);

  transpose_v<<<dim3(32, 48), 256, 0, stream>>>(qkvb, VT);

  attn_mfma<<<768, 256, 0, stream>>>(qkvb, VT);

  gemm_bt<float><<<dim3(768/128, 8192/128), 256, 0, stream>>>(
      qkvb, Wt_proj, b_proj, out, 8192, 768, 768, 2304);
}